// Round 11
// baseline (160.189 us; speedup 1.0000x reference)
//
#include <hip/hip_runtime.h>
#include <hip/hip_bf16.h>

#define KD 128   // KEY_DIM
#define VD 64    // VALUE_DIM
#define NA 256   // N_ACTIONS
#define NB 32    // B
#define LL 2048  // L

typedef __attribute__((ext_vector_type(8))) short bf16x8;
typedef __attribute__((ext_vector_type(4))) float f32x4;
typedef __attribute__((ext_vector_type(8))) unsigned short u16x8;
typedef __attribute__((ext_vector_type(4))) unsigned short u16x4;

static __device__ __forceinline__ unsigned short f2bf(float x) {
  __hip_bfloat16 h = __float2bfloat16(x);
  unsigned short u;
  __builtin_memcpy(&u, &h, 2);
  return u;
}

static __device__ __forceinline__ void stage16(const void* gsrc, void* ldst) {
  __builtin_amdgcn_global_load_lds(
      (const __attribute__((address_space(1))) void*)gsrc,
      (__attribute__((address_space(3))) void*)ldst, 16, 0, 0);
}

// ---------------------------------------------------------------
// K1: W2[n][a] = sum_k W[n][k][a]   (128 x 256 fp32)
// ---------------------------------------------------------------
__global__ __launch_bounds__(256) void fold_w(const float* __restrict__ W,
                                              float* __restrict__ W2) {
  const int idx = blockIdx.x * 256 + threadIdx.x;   // n*256 + a
  const int n = idx >> 8, a = idx & 255;
  const float* p = W + (long)n * (VD * NA) + a;
  float s = 0.f;
  #pragma unroll
  for (int k = 0; k < VD; ++k) s += p[k * NA];
  W2[idx] = s;
}

// ---------------------------------------------------------------
// K2: Tt[b][d][n] = sum_a W2[n][a] * V[b][a][d]   (bf16 out, transposed)
// ---------------------------------------------------------------
__global__ __launch_bounds__(128) void compute_t(const float* __restrict__ W2,
                                                 const float* __restrict__ V,
                                                 unsigned short* __restrict__ Tt) {
  const int n = threadIdx.x;
  const int d0 = blockIdx.x * 8;
  const int b = blockIdx.y;
  const float* vb = V + (long)b * NA * KD + d0;
  const float* w2p = W2 + n * NA;
  float acc[8] = {0.f, 0.f, 0.f, 0.f, 0.f, 0.f, 0.f, 0.f};
  for (int a = 0; a < NA; a += 4) {
    const float4 w = *(const float4*)(w2p + a);
    const float wq[4] = {w.x, w.y, w.z, w.w};
    #pragma unroll
    for (int q = 0; q < 4; ++q) {
      const float* vr = vb + (long)(a + q) * KD;
      #pragma unroll
      for (int j = 0; j < 8; ++j) acc[j] += wq[q] * vr[j];
    }
  }
  #pragma unroll
  for (int j = 0; j < 8; ++j)
    Tt[((long)b * KD + d0 + j) * KD + n] = f2bf(acc[j]);
}

// ---------------------------------------------------------------
// K3 (fused cvt_key + gemm_mem): per block (b, mt of 16):
//  - reg-stage 128x128 fp32 key tile -> bf16 -> swizzled ds_write
//    into ldsA AND global-write keyB (byproduct).
//  - stage Tt[b] (32 KB) via global_load_lds.
//  - 128x128 MFMA tile -> memB.
// ---------------------------------------------------------------
__global__ __launch_bounds__(256) void gemm_mem_f(const float* __restrict__ key,
                                                  const unsigned short* __restrict__ Tt,
                                                  unsigned short* __restrict__ keyB,
                                                  unsigned short* __restrict__ memB) {
  __shared__ unsigned short ldsA[16384];  // 32 KB
  __shared__ unsigned short ldsB[16384];  // 32 KB
  const int nper = gridDim.x >> 3;
  const int lg = (blockIdx.x & 7) * nper + (blockIdx.x >> 3);
  const int mt = lg & 15;
  const int b = lg >> 4;

  const int tid = threadIdx.x;
  const int lane = tid & 63, w = tid >> 6;
  const int l15 = lane & 15, lhi = lane >> 4;

  const float* gK = key + ((long)b * LL + mt * 128) * KD;
  unsigned short* gKB = keyB + ((long)b * LL + mt * 128) * KD;
  const unsigned short* gB = Tt + (long)b * KD * KD;

  #pragma unroll
  for (int i = 0; i < 8; ++i) {
    const int addr = (w * 8 + i) * 1024 + lane * 16;
    const int row = addr >> 8;
    const int src = addr ^ ((row & 7) << 4);
    stage16((const char*)gB + src, (char*)ldsB + addr);
  }
  #pragma unroll
  for (int it = 0; it < 8; ++it) {
    const int idx = it * 256 + tid;     // 2048 groups of 8 elems
    const int row = idx >> 4;           // 0..127
    const int c8 = idx & 15;            // 16 groups per row
    const float4 f0 = *(const float4*)(gK + row * KD + c8 * 8);
    const float4 f1 = *(const float4*)(gK + row * KD + c8 * 8 + 4);
    u16x8 v;
    v[0] = f2bf(f0.x); v[1] = f2bf(f0.y); v[2] = f2bf(f0.z); v[3] = f2bf(f0.w);
    v[4] = f2bf(f1.x); v[5] = f2bf(f1.y); v[6] = f2bf(f1.z); v[7] = f2bf(f1.w);
    *(u16x8*)(gKB + row * KD + c8 * 8) = v;
    const int byte = (row * 256 + c8 * 16) ^ ((row & 7) << 4);
    *(u16x8*)((char*)ldsA + byte) = v;
  }
  __syncthreads();

  const int wr = w >> 1, wc = w & 1;
  f32x4 acc[4][4];
  #pragma unroll
  for (int i = 0; i < 4; ++i)
    #pragma unroll
    for (int j = 0; j < 4; ++j) acc[i][j] = f32x4{0.f, 0.f, 0.f, 0.f};

  #pragma unroll
  for (int ks = 0; ks < 4; ++ks) {
    const int kb = (ks * 32 + lhi * 8) * 2;
    bf16x8 av[4], bv[4];
    #pragma unroll
    for (int mf = 0; mf < 4; ++mf) {
      const int row = wr * 64 + mf * 16 + l15;
      const int byte = (row * 256 + kb) ^ ((row & 7) << 4);
      av[mf] = *(const bf16x8*)((const char*)ldsA + byte);
    }
    #pragma unroll
    for (int nf = 0; nf < 4; ++nf) {
      const int row = wc * 64 + nf * 16 + l15;
      const int byte = (row * 256 + kb) ^ ((row & 7) << 4);
      bv[nf] = *(const bf16x8*)((const char*)ldsB + byte);
    }
    #pragma unroll
    for (int mf = 0; mf < 4; ++mf)
      #pragma unroll
      for (int nf = 0; nf < 4; ++nf)
        acc[mf][nf] = __builtin_amdgcn_mfma_f32_16x16x32_bf16(bv[nf], av[mf],
                                                              acc[mf][nf], 0, 0, 0);
  }

  const long row0 = (long)b * LL + mt * 128 + wr * 64;
  const int col0 = wc * 64;
  #pragma unroll
  for (int mf = 0; mf < 4; ++mf)
    #pragma unroll
    for (int nf = 0; nf < 4; ++nf) {
      const long r = row0 + mf * 16 + l15;
      const int c = col0 + nf * 16 + lhi * 4;
      u16x4 v;
      #pragma unroll
      for (int i = 0; i < 4; ++i) v[i] = f2bf(acc[mf][nf][i]);
      *(u16x4*)(memB + r * KD + c) = v;
    }
}

// ---------------------------------------------------------------
// K5: q GEMM, B-resident + TRIPLE-BUFFERED A (prefetch depth 2).
// 256 blocks (1/CU), block = (b, nt). B panel 64 KB resident;
// A tiles BM=128 (32 KB) ring A0/A1/A2 over 16 mt gens. Per gen t:
//   issue stage A(t+2) -> compute from A[t%3] -> 16 stores ->
//   vmcnt(N) -> s_barrier
// Loads for gen t+1 were issued at top of gen t-1: a FULL generation
// (~5 us) of cover vs HBM read latency under the store stream.
// vmcnt N = #VMEM issued after L(t+1) (in-order retire):
//   t=0: L(2)4+S(0)16 = 20;  1<=t<=13: S(t-1)16+L(t+2)4+S(t)16 = 36;
//   t=14: S(13)16+S(14)16 = 32;  t=15: none (kernel end drains).
// Stores never drained in-loop; backlog <= 2 gens.
// LDS total = 64 + 3*32 = 160 KB (full CU allotment, 1 block/CU).
// ---------------------------------------------------------------
__global__ __launch_bounds__(512, 2) void gemm_q(const unsigned short* __restrict__ A,
                                                 const unsigned short* __restrict__ Bm,
                                                 float* __restrict__ C) {
  __shared__ unsigned short ldsB[32768];   // B panel 64 KB (resident)
  __shared__ unsigned short ldsA0[16384];  // A ring 3 x 32 KB
  __shared__ unsigned short ldsA1[16384];
  __shared__ unsigned short ldsA2[16384];

  // 256 blocks: xcd = bid % 8 owns 32 logical = 4 whole batches
  const int lg = (blockIdx.x & 7) * 32 + (blockIdx.x >> 3);
  const int nt = lg & 7;
  const int b = lg >> 3;

  const int tid = threadIdx.x;
  const int lane = tid & 63, w = tid >> 6;     // 8 waves
  const int l15 = lane & 15, lhi = lane >> 4;
  const int wrM = w >> 2;                      // 0..1 : 64-row half
  const int wcN = w & 3;                       // 0..3 : 64-col block

  const unsigned short* gB = Bm + ((long)b * LL + nt * 256) * KD;
  const unsigned short* gAb = A + (long)b * LL * KD;

  // ---- prologue: B panel + A(0) + A(1); wait all but A(1) ----
  #pragma unroll
  for (int i = 0; i < 8; ++i) {
    const int addr = i * 8192 + tid * 16;
    const int row = addr >> 8;
    const int src = addr ^ ((row & 7) << 4);
    stage16((const char*)gB + src, (char*)ldsB + addr);
  }
  #pragma unroll
  for (int i = 0; i < 4; ++i) {
    const int addr = i * 8192 + tid * 16;
    const int row = addr >> 8;
    const int src = addr ^ ((row & 7) << 4);
    stage16((const char*)gAb + src, (char*)ldsA0 + addr);
  }
  #pragma unroll
  for (int i = 0; i < 4; ++i) {
    const int addr = i * 8192 + tid * 16;
    const int row = addr >> 8;
    const int src = addr ^ ((row & 7) << 4);
    stage16((const char*)(gAb + (long)128 * KD) + src, (char*)ldsA1 + addr);
  }
  asm volatile("s_waitcnt vmcnt(4)" ::: "memory");  // B + A0 done, A1 in flight
  __builtin_amdgcn_s_barrier();
  __builtin_amdgcn_sched_barrier(0);

  const int col0 = nt * 256 + wcN * 64;

  auto gen = [&](int mt, const unsigned short* abuf, unsigned short* nbuf) {
    // ---- issue A(mt+2) stage FIRST (oldest VMEM this gen) ----
    if (mt < 14) {
      const char* gA = (const char*)(gAb + (long)(mt + 2) * 128 * KD);
      #pragma unroll
      for (int i = 0; i < 4; ++i) {
        const int addr = i * 8192 + tid * 16;
        const int row = addr >> 8;
        const int src = addr ^ ((row & 7) << 4);
        stage16(gA + src, (char*)nbuf + addr);
      }
    }
    __builtin_amdgcn_sched_barrier(0);

    // ---- compute 128x256 from abuf + ldsB ----
    f32x4 acc[4][4];
    #pragma unroll
    for (int i = 0; i < 4; ++i)
      #pragma unroll
      for (int j = 0; j < 4; ++j) acc[i][j] = f32x4{0.f, 0.f, 0.f, 0.f};

    #pragma unroll
    for (int ks = 0; ks < 4; ++ks) {
      const int kb = (ks * 32 + lhi * 8) * 2;
      bf16x8 av[4], bv[4];
      #pragma unroll
      for (int mf = 0; mf < 4; ++mf) {
        const int row = wrM * 64 + mf * 16 + l15;
        const int byte = (row * 256 + kb) ^ ((row & 7) << 4);
        av[mf] = *(const bf16x8*)((const char*)abuf + byte);
      }
      #pragma unroll
      for (int nf = 0; nf < 4; ++nf) {
        const int row = wcN * 64 + nf * 16 + l15;
        const int byte = (row * 256 + kb) ^ ((row & 7) << 4);
        bv[nf] = *(const bf16x8*)((const char*)ldsB + byte);
      }
      // swapped operands: lane&15 = out row, (lane>>4)*4+reg = out col
      #pragma unroll
      for (int mf = 0; mf < 4; ++mf)
        #pragma unroll
        for (int nf = 0; nf < 4; ++nf)
          acc[mf][nf] = __builtin_amdgcn_mfma_f32_16x16x32_bf16(bv[nf], av[mf],
                                                                acc[mf][nf], 0, 0, 0);
    }

    // ---- 16 cached dwordx4 stores (fire and forget) ----
    const long row0 = (long)b * LL + mt * 128 + wrM * 64;
    #pragma unroll
    for (int mf = 0; mf < 4; ++mf)
      #pragma unroll
      for (int nf = 0; nf < 4; ++nf) {
        const long r = row0 + mf * 16 + l15;
        const int c = col0 + nf * 16 + lhi * 4;
        *(f32x4*)(C + r * LL + c) = acc[mf][nf];
      }

    // ---- end-of-gen: ensure A(mt+1) landed; keep stores in flight ----
    if (mt < 15) {
      if (mt == 0) {
        asm volatile("s_waitcnt vmcnt(20)" ::: "memory");
      } else if (mt == 14) {
        asm volatile("s_waitcnt vmcnt(32)" ::: "memory");
      } else {
        asm volatile("s_waitcnt vmcnt(36)" ::: "memory");
      }
      __builtin_amdgcn_sched_barrier(0);
      __builtin_amdgcn_s_barrier();
      __builtin_amdgcn_sched_barrier(0);
    }
  };

  // ring: abuf = A[mt%3], nbuf = A[(mt+2)%3]
  #pragma unroll 1
  for (int c3 = 0; c3 < 5; ++c3) {
    gen(3 * c3 + 0, ldsA0, ldsA2);
    gen(3 * c3 + 1, ldsA1, ldsA0);
    gen(3 * c3 + 2, ldsA2, ldsA1);
  }
  gen(15, ldsA0, ldsA2);  // 15 % 3 == 0; no stage, no wait
}

// ---------------------------------------------------------------
// launch
// ---------------------------------------------------------------
extern "C" void kernel_launch(void* const* d_in, const int* in_sizes, int n_in,
                              void* d_out, int out_size, void* d_ws, size_t ws_size,
                              hipStream_t stream) {
  const float* key = (const float*)d_in[0];  // (32, 2048, 128)
  const float* val = (const float*)d_in[1];  // (32, 256, 128)
  const float* wts = (const float*)d_in[2];  // (128, 64, 256)
  float* out = (float*)d_out;                // (32, 2048, 2048) fp32

  // workspace layout (total ~33.1 MiB)
  char* ws = (char*)d_ws;
  float* W2 = (float*)ws;                                        // 128 KiB
  unsigned short* Tt = (unsigned short*)(ws + 131072);           // 1 MiB
  unsigned short* keyB = (unsigned short*)(ws + 131072 + 1048576);            // 16 MiB
  unsigned short* memB = (unsigned short*)(ws + 131072 + 1048576 + 16777216); // 16 MiB

  fold_w<<<128, 256, 0, stream>>>(wts, W2);
  compute_t<<<dim3(16, NB), 128, 0, stream>>>(W2, val, Tt);
  gemm_mem_f<<<16 * NB, 256, 0, stream>>>(key, Tt, keyB, memB);
  gemm_q<<<8 * NB, 512, 0, stream>>>(keyB, memB, out);
}

// Round 13
// 153.748 us; speedup vs baseline: 1.0419x; 1.0419x over previous
//
#include <hip/hip_runtime.h>
#include <hip/hip_bf16.h>

#define KD 128   // KEY_DIM
#define VD 64    // VALUE_DIM
#define NA 256   // N_ACTIONS
#define NB 32    // B
#define LL 2048  // L

typedef __attribute__((ext_vector_type(8))) short bf16x8;
typedef __attribute__((ext_vector_type(4))) float f32x4;
typedef __attribute__((ext_vector_type(8))) unsigned short u16x8;
typedef __attribute__((ext_vector_type(4))) unsigned short u16x4;

static __device__ __forceinline__ unsigned short f2bf(float x) {
  __hip_bfloat16 h = __float2bfloat16(x);
  unsigned short u;
  __builtin_memcpy(&u, &h, 2);
  return u;
}

static __device__ __forceinline__ void stage16(const void* gsrc, void* ldst) {
  __builtin_amdgcn_global_load_lds(
      (const __attribute__((address_space(1))) void*)gsrc,
      (__attribute__((address_space(3))) void*)ldst, 16, 0, 0);
}

// ---------------------------------------------------------------
// K1: W2[n][a] = sum_k W[n][k][a]   (128 x 256 fp32)
// ---------------------------------------------------------------
__global__ __launch_bounds__(256) void fold_w(const float* __restrict__ W,
                                              float* __restrict__ W2) {
  const int idx = blockIdx.x * 256 + threadIdx.x;   // n*256 + a
  const int n = idx >> 8, a = idx & 255;
  const float* p = W + (long)n * (VD * NA) + a;
  float s = 0.f;
  #pragma unroll
  for (int k = 0; k < VD; ++k) s += p[k * NA];
  W2[idx] = s;
}

// ---------------------------------------------------------------
// K2: Tt[b][d][n] = sum_a W2[n][a] * V[b][a][d]   (bf16 out, transposed)
// ---------------------------------------------------------------
__global__ __launch_bounds__(128) void compute_t(const float* __restrict__ W2,
                                                 const float* __restrict__ V,
                                                 unsigned short* __restrict__ Tt) {
  const int n = threadIdx.x;
  const int d0 = blockIdx.x * 8;
  const int b = blockIdx.y;
  const float* vb = V + (long)b * NA * KD + d0;
  const float* w2p = W2 + n * NA;
  float acc[8] = {0.f, 0.f, 0.f, 0.f, 0.f, 0.f, 0.f, 0.f};
  for (int a = 0; a < NA; a += 4) {
    const float4 w = *(const float4*)(w2p + a);
    const float wq[4] = {w.x, w.y, w.z, w.w};
    #pragma unroll
    for (int q = 0; q < 4; ++q) {
      const float* vr = vb + (long)(a + q) * KD;
      #pragma unroll
      for (int j = 0; j < 8; ++j) acc[j] += wq[q] * vr[j];
    }
  }
  #pragma unroll
  for (int j = 0; j < 8; ++j)
    Tt[((long)b * KD + d0 + j) * KD + n] = f2bf(acc[j]);
}

// ---------------------------------------------------------------
// K3: key fp32 -> bf16, 8 elements/thread
// ---------------------------------------------------------------
__global__ __launch_bounds__(256) void cvt_key(const float* __restrict__ in,
                                               unsigned short* __restrict__ out) {
  const long i = ((long)blockIdx.x * 256 + threadIdx.x) * 8;
  const float4 f0 = *(const float4*)(in + i);
  const float4 f1 = *(const float4*)(in + i + 4);
  u16x8 r;
  r[0] = f2bf(f0.x); r[1] = f2bf(f0.y); r[2] = f2bf(f0.z); r[3] = f2bf(f0.w);
  r[4] = f2bf(f1.x); r[5] = f2bf(f1.y); r[6] = f2bf(f1.z); r[7] = f2bf(f1.w);
  *(u16x8*)(out + i) = r;
}

// ---------------------------------------------------------------
// K4: FUSED q GEMM. Block (b, nt), 256 blocks (1/CU), 512 threads.
// Prologue: stage Tt[b] (32 KB -> low ldsB) + keyB chunk rows
//   [nt*256,+256) (64 KB -> A0|A1); compute the block's own B-panel
//   memB-rows = chunk @ Tt^T (64 MFMA/wave) in registers; convert to
//   bf16; swizzled ds_write into ldsB [256 rows][128 d]. memB never
//   touches HBM. Then the ROUND-10 mt-loop exactly: B-resident, A
//   2-buffer dbuf with stage A(mt+1) per gen (NOT mt+2 — round-12 bug),
//   counted vmcnt(16), raw s_barrier, cached dwordx4 stores.
// LDS: ldsB 64 KB + A0/A1 2x32 KB = 128 KB.
// ---------------------------------------------------------------
__global__ __launch_bounds__(512, 2) void gemm_q(const unsigned short* __restrict__ A,
                                                 const unsigned short* __restrict__ Tt,
                                                 float* __restrict__ C) {
  __shared__ unsigned short ldsB[32768];   // B panel 64 KB (resident after prologue)
  __shared__ unsigned short ldsA0[16384];  // A tile 32 KB (ping)
  __shared__ unsigned short ldsA1[16384];  // A tile 32 KB (pong)

  // 256 blocks: xcd = bid % 8 owns 32 logical = 4 whole batches
  const int lg = (blockIdx.x & 7) * 32 + (blockIdx.x >> 3);
  const int nt = lg & 7;
  const int b = lg >> 3;

  const int tid = threadIdx.x;
  const int lane = tid & 63, w = tid >> 6;     // 8 waves
  const int l15 = lane & 15, lhi = lane >> 4;
  const int wrM = w >> 2;                      // 0..1 : 64-row half (main loop)
  const int wcN = w & 3;                       // 0..3 : 64-col block (main loop)

  const unsigned short* gAb = A + (long)b * LL * KD;                 // keyB[b]
  const unsigned short* gT = Tt + (long)b * KD * KD;                 // Tt[b]
  const unsigned short* gChunk = gAb + (long)nt * 256 * KD;          // B-source rows

  // ---- prologue 1: stage Tt (32 KB -> ldsB low) + chunk (64 KB -> A0|A1) ----
  #pragma unroll
  for (int i = 0; i < 4; ++i) {
    const int addr = i * 8192 + tid * 16;
    const int row = addr >> 8;
    const int src = addr ^ ((row & 7) << 4);
    stage16((const char*)gT + src, (char*)ldsB + addr);
  }
  #pragma unroll
  for (int i = 0; i < 8; ++i) {
    const int addr = i * 8192 + tid * 16;      // 0..64 KB over chunk
    const int row = addr >> 8;
    const int src = addr ^ ((row & 7) << 4);
    char* dst = (addr < 32768) ? ((char*)ldsA0 + addr) : ((char*)ldsA1 + addr - 32768);
    stage16((const char*)gChunk + src, dst);
  }
  asm volatile("s_waitcnt vmcnt(0)" ::: "memory");
  __builtin_amdgcn_s_barrier();
  __builtin_amdgcn_sched_barrier(0);

  // ---- prologue 2: B-panel = chunk (256x128) @ Tt^T (128x128) in regs ----
  // wave w owns chunk rows [w*32, w*32+32): 2 row-frags x 8 d-frags.
  f32x4 pacc[2][8];
  #pragma unroll
  for (int i = 0; i < 2; ++i)
    #pragma unroll
    for (int j = 0; j < 8; ++j) pacc[i][j] = f32x4{0.f, 0.f, 0.f, 0.f};

  #pragma unroll
  for (int ks = 0; ks < 4; ++ks) {
    const int kb = (ks * 32 + lhi * 8) * 2;
    bf16x8 av[2], bv[8];
    #pragma unroll
    for (int rf = 0; rf < 2; ++rf) {
      const int row = w * 32 + rf * 16 + l15;          // 0..255 in chunk
      const int byte = (row * 256 + kb) ^ ((row & 7) << 4);
      av[rf] = (row < 128)
          ? *(const bf16x8*)((const char*)ldsA0 + byte)
          : *(const bf16x8*)((const char*)ldsA1 + (byte - 32768));
    }
    #pragma unroll
    for (int df = 0; df < 8; ++df) {
      const int row = df * 16 + l15;                   // Tt row = d
      const int byte = (row * 256 + kb) ^ ((row & 7) << 4);
      bv[df] = *(const bf16x8*)((const char*)ldsB + byte);
    }
    #pragma unroll
    for (int rf = 0; rf < 2; ++rf)
      #pragma unroll
      for (int df = 0; df < 8; ++df)
        pacc[rf][df] = __builtin_amdgcn_mfma_f32_16x16x32_bf16(bv[df], av[rf],
                                                               pacc[rf][df], 0, 0, 0);
  }
  // all waves done reading ldsB(Tt)/A0/A1 once past this barrier
  asm volatile("s_waitcnt lgkmcnt(0)" ::: "memory");
  __builtin_amdgcn_sched_barrier(0);
  __builtin_amdgcn_s_barrier();
  __builtin_amdgcn_sched_barrier(0);

  // ---- prologue 3: issue A(0) stage FIRST, then ds_write B-panel ----
  #pragma unroll
  for (int i = 0; i < 4; ++i) {
    const int addr = i * 8192 + tid * 16;
    const int row = addr >> 8;
    const int src = addr ^ ((row & 7) << 4);
    stage16((const char*)gAb + src, (char*)ldsA0 + addr);
  }
  __builtin_amdgcn_sched_barrier(0);
  // B-panel frag: lane&15 = chunk-row (within 16), lhi*4+reg = d col.
  #pragma unroll
  for (int rf = 0; rf < 2; ++rf)
    #pragma unroll
    for (int df = 0; df < 8; ++df) {
      const int row = w * 32 + rf * 16 + l15;          // 0..255
      const int d = df * 16 + lhi * 4;
      u16x4 v;
      #pragma unroll
      for (int i = 0; i < 4; ++i) v[i] = f2bf(pacc[rf][df][i]);
      const int byte = (row * 256 + d * 2) ^ ((row & 7) << 4);
      *(u16x4*)((char*)ldsB + byte) = v;
    }
  asm volatile("s_waitcnt vmcnt(0) lgkmcnt(0)" ::: "memory");
  __builtin_amdgcn_sched_barrier(0);
  __builtin_amdgcn_s_barrier();
  __builtin_amdgcn_sched_barrier(0);

  const int col0 = nt * 256 + wcN * 64;

  // ---- main loop: ROUND-10 schedule (validated) ----
  auto gen = [&](int mt, const unsigned short* abuf, unsigned short* nbuf) {
    // issue next-gen A(mt+1) stage FIRST (oldest in VM queue)
    if (mt < 15) {
      const char* gA = (const char*)(gAb + (long)(mt + 1) * 128 * KD);
      #pragma unroll
      for (int i = 0; i < 4; ++i) {
        const int addr = i * 8192 + tid * 16;
        const int row = addr >> 8;
        const int src = addr ^ ((row & 7) << 4);
        stage16(gA + src, (char*)nbuf + addr);
      }
    }
    __builtin_amdgcn_sched_barrier(0);

    // compute 128x256 from abuf + ldsB
    f32x4 acc[4][4];
    #pragma unroll
    for (int i = 0; i < 4; ++i)
      #pragma unroll
      for (int j = 0; j < 4; ++j) acc[i][j] = f32x4{0.f, 0.f, 0.f, 0.f};

    #pragma unroll
    for (int ks = 0; ks < 4; ++ks) {
      const int kb = (ks * 32 + lhi * 8) * 2;
      bf16x8 av[4], bv[4];
      #pragma unroll
      for (int mf = 0; mf < 4; ++mf) {
        const int row = wrM * 64 + mf * 16 + l15;
        const int byte = (row * 256 + kb) ^ ((row & 7) << 4);
        av[mf] = *(const bf16x8*)((const char*)abuf + byte);
      }
      #pragma unroll
      for (int nf = 0; nf < 4; ++nf) {
        const int row = wcN * 64 + nf * 16 + l15;
        const int byte = (row * 256 + kb) ^ ((row & 7) << 4);
        bv[nf] = *(const bf16x8*)((const char*)ldsB + byte);
      }
      // swapped operands: lane&15 = out row, (lane>>4)*4+reg = out col
      #pragma unroll
      for (int mf = 0; mf < 4; ++mf)
        #pragma unroll
        for (int nf = 0; nf < 4; ++nf)
          acc[mf][nf] = __builtin_amdgcn_mfma_f32_16x16x32_bf16(bv[nf], av[mf],
                                                                acc[mf][nf], 0, 0, 0);
    }

    // 16 cached dwordx4 stores (fire and forget)
    const long row0 = (long)b * LL + mt * 128 + wrM * 64;
    #pragma unroll
    for (int mf = 0; mf < 4; ++mf)
      #pragma unroll
      for (int nf = 0; nf < 4; ++nf) {
        const long r = row0 + mf * 16 + l15;
        const int c = col0 + nf * 16 + lhi * 4;
        *(f32x4*)(C + r * LL + c) = acc[mf][nf];
      }

    // end-of-gen: drain loads(mt+1)+stores(mt-1), keep stores(mt) in flight
    if (mt < 15) {
      asm volatile("s_waitcnt vmcnt(16)" ::: "memory");
      __builtin_amdgcn_sched_barrier(0);
      __builtin_amdgcn_s_barrier();
      __builtin_amdgcn_sched_barrier(0);
    }
  };

  #pragma unroll 1
  for (int mt2 = 0; mt2 < 8; ++mt2) {
    gen(2 * mt2, ldsA0, ldsA1);
    gen(2 * mt2 + 1, ldsA1, ldsA0);
  }
}

// ---------------------------------------------------------------
// launch
// ---------------------------------------------------------------
extern "C" void kernel_launch(void* const* d_in, const int* in_sizes, int n_in,
                              void* d_out, int out_size, void* d_ws, size_t ws_size,
                              hipStream_t stream) {
  const float* key = (const float*)d_in[0];  // (32, 2048, 128)
  const float* val = (const float*)d_in[1];  // (32, 256, 128)
  const float* wts = (const float*)d_in[2];  // (128, 64, 256)
  float* out = (float*)d_out;                // (32, 2048, 2048) fp32

  // workspace layout
  char* ws = (char*)d_ws;
  float* W2 = (float*)ws;                                        // 128 KiB
  unsigned short* Tt = (unsigned short*)(ws + 131072);           // 1 MiB
  unsigned short* keyB = (unsigned short*)(ws + 131072 + 1048576);  // 16 MiB

  fold_w<<<128, 256, 0, stream>>>(wts, W2);
  cvt_key<<<4096, 256, 0, stream>>>(key, keyB);
  compute_t<<<dim3(16, NB), 128, 0, stream>>>(W2, val, Tt);
  gemm_q<<<8 * NB, 512, 0, stream>>>(keyB, Tt, out);
}